// Round 11
// baseline (221.274 us; speedup 1.0000x reference)
//
#include <hip/hip_runtime.h>
#include <cstddef>
#include <cstdint>

// Problem constants: S=8, N=50000, F=5, DEG=32, D_IN=D_OUT=128
static constexpr int S_    = 8;
static constexpr int N_    = 50000;
static constexpr int F_    = 5;
static constexpr int DEG_  = 32;
static constexpr int DOUT_ = 128;
static constexpr int TOTAL_NODES = S_ * N_;      // 400000

// LDS double-buffer geometry
static constexpr int BLK      = 512;             // threads/block = 8 waves
static constexpr int BPSAMP   = 98;              // blocks/sample (97*512+336)
static constexpr int SLICE    = 6250;            // rows per pass
static constexpr int NPASS    = 8;               // 8*6250 = 50000 exact
static constexpr int SLICE_DW = SLICE * 3;       // 18750 dwords (12B rows)
static constexpr int BUF_DW   = SLICE_DW + 4;    // +dummy row(3) +pad -> 18754 (even)
static constexpr int SLICE_Q  = SLICE_DW / 2;    // 9375 i32x2 per slice
static constexpr int NSTG     = 19;              // ceil(9375/512)

typedef float    f32x4 __attribute__((ext_vector_type(4)));
typedef int      i32x2 __attribute__((ext_vector_type(2)));
typedef int      i32x4 __attribute__((ext_vector_type(4)));
typedef _Float16 h2    __attribute__((ext_vector_type(2)));

// ---------------------------------------------------------------------------
// Kernel 1: fuse W_1 [5][128] with W [256][128] into Wc [2][5][128].
// ---------------------------------------------------------------------------
__global__ void wc_precompute(const float* __restrict__ W1,
                              const float* __restrict__ W,
                              float* __restrict__ Wc) {
    int t = blockIdx.x * blockDim.x + threadIdx.x;
    if (t >= 2 * F_ * DOUT_) return;
    int o = t & (DOUT_ - 1);
    int f = (t >> 7) % F_;
    int p = t / (F_ * DOUT_);
    const float* w1r  = W1 + f * 128;
    const float* wcol = W + (size_t)p * 128 * DOUT_ + o;
    float acc = 0.f;
#pragma unroll 8
    for (int d = 0; d < 128; ++d)
        acc = fmaf(w1r[d], wcol[(size_t)d * DOUT_], acc);
    Wc[t] = acc;
}

// ---------------------------------------------------------------------------
// Kernel 2: pack x rows into 12B f16 rows (f0..f4 + zero pad half).
// ---------------------------------------------------------------------------
__global__ __launch_bounds__(256) void xpack_h6(const float* __restrict__ x,
                                                int* __restrict__ xh6) {
    int t = blockIdx.x * blockDim.x + threadIdx.x;
    if (t >= TOTAL_NODES) return;
    const float* r = x + (size_t)t * F_;
    h2 p0 = { (_Float16)r[0], (_Float16)r[1] };
    h2 p1 = { (_Float16)r[2], (_Float16)r[3] };
    h2 p2 = { (_Float16)r[4], (_Float16)0.f };
    xh6[3 * t + 0] = __builtin_bit_cast(int, p0);
    xh6[3 * t + 1] = __builtin_bit_cast(int, p1);
    xh6[3 * t + 2] = __builtin_bit_cast(int, p2);
}

// ---------------------------------------------------------------------------
// Kernel 3: encoder v11 — LDS double-buffered staged gather (T14 split).
//   Block = 512 consecutive nodes of one sample; thread = node.
//   8 passes over the sample's 50000-row f16 table, slice = 6250 rows (75KB);
//   two slices resident (150KB). Per pass: issue next slice's global loads ->
//   gather current slice (branchless clamp to zeroed dummy row) -> ds_write
//   next slice -> barrier. Phase B: v10-proven transpose + MLP + nt stores.
// ---------------------------------------------------------------------------
__global__ __launch_bounds__(BLK) void encoder_v11(
    const int*   __restrict__ idx,   // [S][N][32]
    const int*   __restrict__ xh6,   // [S*N][3] dwords (f16x6 rows)
    const float* __restrict__ x,     // [S][N][5] fp32 (self, exact)
    const float* __restrict__ Wc,    // [2][5][128]
    const float* __restrict__ b,     // [128]
    float* __restrict__ out) {       // [S][N][128]
    __shared__ i32x2 ldsbuf[BUF_DW];             // 2 buffers, 8B-aligned
    int* __restrict__ ldsi = (int*)ldsbuf;       // 2*18754 dwords = 150032 B
    const int tid = threadIdx.x;
    const int s   = blockIdx.x / BPSAMP;
    const int blk = blockIdx.x % BPSAMP;
    const int nl  = blk * BLK + tid;             // local node
    const bool valid = nl < N_;
    const int  node  = s * N_ + (valid ? nl : (N_ - 1));

    // --- all 32 neighbor ids -> registers (coalesced 128B/thread) ---
    i32x4 ids[8];
    const i32x4* irow = reinterpret_cast<const i32x4*>(idx + (size_t)node * DEG_);
#pragma unroll
    for (int t = 0; t < 8; ++t)
        ids[t] = __builtin_nontemporal_load(irow + t);

    // zero the two dummy rows (row index SLICE in each buffer)
    if (tid < 3) { ldsi[SLICE_DW + tid] = 0; ldsi[BUF_DW * 2 /*dw: 18754*2? no*/]; }
    // (the line above is replaced below — keep single clear path)
    if (tid < 3) {
        ldsi[SLICE_DW + tid] = 0;                 // buf0 dummy @ dw 18750..18752
        ldsi[BUF_DW * 2 - 4 + tid] = 0;           // placeholder overwritten next
    }
    if (tid < 3) ldsi[18754 + SLICE_DW + tid] = 0; // buf1 dummy @ dw 37504..37506

    const i32x2* __restrict__ tab2 =
        reinterpret_cast<const i32x2*>(xh6) + (size_t)s * (SLICE_Q * NPASS);

    // ---- staging helpers (register-split per T14) ----
    i32x2 streg[NSTG];
#define STAGE_LOAD(P)                                                         \
    { const i32x2* ps_ = tab2 + (P) * SLICE_Q;                                \
      _Pragma("unroll")                                                       \
      for (int u = 0; u < NSTG; ++u) {                                        \
          const int i_ = tid + BLK * u;                                       \
          if (u < NSTG - 1 || i_ < SLICE_Q) streg[u] = ps_[i_];               \
      } }
#define STAGE_WRITE(BUFQ)                                                     \
    { i32x2* d_ = ldsbuf + (BUFQ);                                            \
      _Pragma("unroll")                                                       \
      for (int u = 0; u < NSTG; ++u) {                                        \
          const int i_ = tid + BLK * u;                                       \
          if (u < NSTG - 1 || i_ < SLICE_Q) d_[i_] = streg[u];                \
      } }

    // prologue: slice 0 into buffer 0
    STAGE_LOAD(0);
    STAGE_WRITE(0);
    __syncthreads();

    h2 a0 = { (_Float16)0.f, (_Float16)0.f };
    h2 a1 = a0, a2 = a0;

#pragma unroll 2
    for (int p = 0; p < NPASS; ++p) {
        const int curdw = (p & 1) ? 18754 : 0;       // current buffer dword base
        const int nxtq  = (p & 1) ? 0 : 9377;        // next buffer i32x2 base
        if (p + 1 < NPASS) STAGE_LOAD(p + 1);        // issue early (T14)
        const int lo = p * SLICE;
#pragma unroll
        for (int k = 0; k < DEG_; ++k) {
            const int id = ids[k >> 2][k & 3];
            const unsigned d = (unsigned)(id - lo);
            const int r = (d < (unsigned)SLICE) ? (int)d : SLICE;  // clamp->0 row
            const int ba = curdw + r * 3;
            const int w0 = ldsi[ba], w1 = ldsi[ba + 1], w2 = ldsi[ba + 2];
            a0 += __builtin_bit_cast(h2, w0);
            a1 += __builtin_bit_cast(h2, w1);
            a2 += __builtin_bit_cast(h2, w2);
        }
        if (p + 1 < NPASS) STAGE_WRITE(nxtq);        // write late (after gather)
        __syncthreads();
    }

    // ---- transpose sums via LDS (pass data dead) ----
    ldsi[tid * 3 + 0] = __builtin_bit_cast(int, a0);
    ldsi[tid * 3 + 1] = __builtin_bit_cast(int, a1);
    ldsi[tid * 3 + 2] = __builtin_bit_cast(int, a2);
    __syncthreads();

    // ---- Phase B: MLP + relu + nt store (v10-proven) ----
    const int lane = tid & 63;
    const int wv   = tid >> 6;                   // 0..7, wave covers 64 nodes
    const int sl   = lane & 31;
    const int half = lane >> 5;
    const int o0   = sl << 2;
    const float inv = 1.f / DEG_;

    float wa[F_][4], wb[F_][4];
#pragma unroll
    for (int f = 0; f < F_; ++f) {
        f32x4 a  = *reinterpret_cast<const f32x4*>(Wc + f * DOUT_ + o0);
        f32x4 bb = *reinterpret_cast<const f32x4*>(Wc + F_ * DOUT_ + f * DOUT_ + o0);
        wa[f][0] = a.x;        wa[f][1] = a.y;
        wa[f][2] = a.z;        wa[f][3] = a.w;
        wb[f][0] = bb.x * inv; wb[f][1] = bb.y * inv;   // fold mean(1/32)
        wb[f][2] = bb.z * inv; wb[f][3] = bb.w * inv;
    }
    const f32x4 bias = *reinterpret_cast<const f32x4*>(b + o0);

#pragma unroll 4
    for (int i = 0; i < 32; ++i) {
        const int nlb = wv * 64 + 2 * i + half;      // local node in block
        const int n   = blk * BLK + nlb;
        if (n >= N_) continue;                       // tail block only
        const int gn  = s * N_ + n;
        const h2 b0 = __builtin_bit_cast(h2, ldsi[nlb * 3 + 0]);
        const h2 b1 = __builtin_bit_cast(h2, ldsi[nlb * 3 + 1]);
        const h2 b2 = __builtin_bit_cast(h2, ldsi[nlb * 3 + 2]);
        const float nf[F_] = { (float)b0.x, (float)b0.y,
                               (float)b1.x, (float)b1.y, (float)b2.x };
        const float* xr = x + (size_t)gn * F_;       // broadcast, exact fp32
        const float sf[F_] = { xr[0], xr[1], xr[2], xr[3], xr[4] };
        float y0 = bias.x, y1 = bias.y, y2 = bias.z, y3 = bias.w;
#pragma unroll
        for (int f = 0; f < F_; ++f) {
            y0 = fmaf(sf[f], wa[f][0], y0); y0 = fmaf(nf[f], wb[f][0], y0);
            y1 = fmaf(sf[f], wa[f][1], y1); y1 = fmaf(nf[f], wb[f][1], y1);
            y2 = fmaf(sf[f], wa[f][2], y2); y2 = fmaf(nf[f], wb[f][2], y2);
            y3 = fmaf(sf[f], wa[f][3], y3); y3 = fmaf(nf[f], wb[f][3], y3);
        }
        f32x4 yv = { fmaxf(y0, 0.f), fmaxf(y1, 0.f),
                     fmaxf(y2, 0.f), fmaxf(y3, 0.f) };
        __builtin_nontemporal_store(yv,
            reinterpret_cast<f32x4*>(out + (size_t)gn * DOUT_ + o0));
    }
#undef STAGE_LOAD
#undef STAGE_WRITE
}

// ---------------------------------------------------------------------------
// Fallback (fp32 fused path) if ws_size is too small.
// ---------------------------------------------------------------------------
__global__ __launch_bounds__(256) void encoder_f32(
    const float* __restrict__ x, const int* __restrict__ idx,
    const float* __restrict__ Wc, const float* __restrict__ b,
    float* __restrict__ out, int total_pairs) {
    const int lane = threadIdx.x & 63;
    const int sl   = lane & 31;
    const int half = lane >> 5;
    const int o0   = sl << 2;
    const int gwave  = (blockIdx.x * blockDim.x + threadIdx.x) >> 6;
    const int nwaves = (gridDim.x * blockDim.x) >> 6;
    float wa[F_][4], wb[F_][4];
#pragma unroll
    for (int f = 0; f < F_; ++f) {
        f32x4 a  = *reinterpret_cast<const f32x4*>(Wc + f * DOUT_ + o0);
        f32x4 bb = *reinterpret_cast<const f32x4*>(Wc + F_ * DOUT_ + f * DOUT_ + o0);
        wa[f][0] = a.x;  wa[f][1] = a.y;  wa[f][2] = a.z;  wa[f][3] = a.w;
        wb[f][0] = bb.x; wb[f][1] = bb.y; wb[f][2] = bb.z; wb[f][3] = bb.w;
    }
    const f32x4 bias = *reinterpret_cast<const f32x4*>(b + o0);
    for (int p = gwave; p < total_pairs; p += nwaves) {
        const int node = p * 2 + half;
        const int s    = node / N_;
        const int nb = idx[(size_t)node * DEG_ + sl];
        const float* xr = x + ((size_t)s * N_ + nb) * F_;
        float n0 = xr[0], n1 = xr[1], n2 = xr[2], n3 = xr[3], n4 = xr[4];
#pragma unroll
        for (int m = 1; m < 32; m <<= 1) {
            n0 += __shfl_xor(n0, m); n1 += __shfl_xor(n1, m); n2 += __shfl_xor(n2, m);
            n3 += __shfl_xor(n3, m); n4 += __shfl_xor(n4, m);
        }
        const float inv = 1.f / DEG_;
        const float nf[F_] = {n0 * inv, n1 * inv, n2 * inv, n3 * inv, n4 * inv};
        const float* xsp = x + (size_t)node * F_;
        const float sf[F_] = {xsp[0], xsp[1], xsp[2], xsp[3], xsp[4]};
        float y0 = bias.x, y1 = bias.y, y2 = bias.z, y3 = bias.w;
#pragma unroll
        for (int f = 0; f < F_; ++f) {
            y0 = fmaf(sf[f], wa[f][0], y0); y0 = fmaf(nf[f], wb[f][0], y0);
            y1 = fmaf(sf[f], wa[f][1], y1); y1 = fmaf(nf[f], wb[f][1], y1);
            y2 = fmaf(sf[f], wa[f][2], y2); y2 = fmaf(nf[f], wb[f][2], y2);
            y3 = fmaf(sf[f], wa[f][3], y3); y3 = fmaf(nf[f], wb[f][3], y3);
        }
        f32x4 yv = { fmaxf(y0, 0.f), fmaxf(y1, 0.f), fmaxf(y2, 0.f), fmaxf(y3, 0.f) };
        *reinterpret_cast<f32x4*>(out + (size_t)node * DOUT_ + o0) = yv;
    }
}

extern "C" void kernel_launch(void* const* d_in, const int* in_sizes, int n_in,
                              void* d_out, int out_size, void* d_ws, size_t ws_size,
                              hipStream_t stream) {
    const float* x   = (const float*)d_in[0];
    const int*   idx = (const int*)  d_in[1];
    const float* W1  = (const float*)d_in[2];
    const float* W   = (const float*)d_in[3];
    const float* b   = (const float*)d_in[4];
    float* out = (float*)d_out;

    const size_t wc_bytes  = (size_t)2 * F_ * DOUT_ * sizeof(float);  // 5120
    const size_t xh6_bytes = (size_t)TOTAL_NODES * 12;                // 4.8 MB
    float* Wc = (float*)d_ws;

    hipLaunchKernelGGL(wc_precompute, dim3(5), dim3(256), 0, stream, W1, W, Wc);

    if (ws_size >= wc_bytes + xh6_bytes) {
        int* xh6 = (int*)((char*)d_ws + wc_bytes);   // 5120 % 16 == 0
        hipLaunchKernelGGL(xpack_h6, dim3((TOTAL_NODES + 255) / 256), dim3(256),
                           0, stream, x, xh6);
        hipLaunchKernelGGL(encoder_v11, dim3(S_ * BPSAMP), dim3(BLK), 0, stream,
                           idx, xh6, x, Wc, b, out);
    } else {
        hipLaunchKernelGGL(encoder_f32, dim3(2048), dim3(256), 0, stream,
                           x, idx, Wc, b, out, TOTAL_NODES / 2);
    }
}

// Round 12
// 113.977 us; speedup vs baseline: 1.9414x; 1.9414x over previous
//
#include <hip/hip_runtime.h>
#include <cstddef>
#include <cstdint>

// Problem constants: S=8, N=50000, F=5, DEG=32, D_IN=D_OUT=128
static constexpr int S_    = 8;
static constexpr int N_    = 50000;
static constexpr int F_    = 5;
static constexpr int DEG_  = 32;
static constexpr int DOUT_ = 128;
static constexpr int TOTAL_NODES = S_ * N_;                   // 400000
static constexpr int NODES_PER_WAVE = 16;                     // 8 chains x 2 halves
static constexpr int GROUPS = TOTAL_NODES / NODES_PER_WAVE;   // 25000 (16 | 50000)

typedef float    f32x4 __attribute__((ext_vector_type(4)));
typedef int      i32x2 __attribute__((ext_vector_type(2)));
typedef _Float16 h2    __attribute__((ext_vector_type(2)));

// ---------------------------------------------------------------------------
// Kernel 1: fuse W_1 [5][128] with W [256][128] into Wc [2][5][128].
// (W_1 @ W_top and W_1 @ W_bot — the whole MLP collapses to 2x [5][128].)
// ---------------------------------------------------------------------------
__global__ void wc_precompute(const float* __restrict__ W1,
                              const float* __restrict__ W,
                              float* __restrict__ Wc) {
    int t = blockIdx.x * blockDim.x + threadIdx.x;
    if (t >= 2 * F_ * DOUT_) return;
    int o = t & (DOUT_ - 1);
    int f = (t >> 7) % F_;
    int p = t / (F_ * DOUT_);
    const float* w1r  = W1 + f * 128;
    const float* wcol = W + (size_t)p * 128 * DOUT_ + o;
    float acc = 0.f;
#pragma unroll 8
    for (int d = 0; d < 128; ++d)
        acc = fmaf(w1r[d], wcol[(size_t)d * DOUT_], acc);
    Wc[t] = acc;
}

// ---------------------------------------------------------------------------
// Kernel 2: pack x rows into 8B fp8-e4m3 rows. Table = 3.2 MB -> L2-resident;
// one aligned 8B load per scattered gather.
// ---------------------------------------------------------------------------
__global__ __launch_bounds__(256) void xpack_fp8(const float* __restrict__ x,
                                                 i32x2* __restrict__ xq) {
    int t = blockIdx.x * blockDim.x + threadIdx.x;
    if (t >= TOTAL_NODES) return;
    const float* r = x + (size_t)t * F_;
    int d0 = __builtin_amdgcn_cvt_pk_fp8_f32(r[0], r[1], 0, false);
    d0     = __builtin_amdgcn_cvt_pk_fp8_f32(r[2], r[3], d0, true);
    int d1 = __builtin_amdgcn_cvt_pk_fp8_f32(r[4], 0.f, 0, false);
    i32x2 v; v.x = d0; v.y = d1;
    xq[t] = v;
}

// ---------------------------------------------------------------------------
// Kernel 3: encoder v12 (= round-6 champion, aux-trimmed).
//   One wave = 16 nodes (8 chains x 2 halves), exact dispatch.
//   All 8 idx loads + 8 scattered fp8 gathers issued up front (MLP);
//   packed-f16 butterfly reduce within 32-lane halves; self features read
//   DIRECTLY from fp32 x (exact); 1/DEG folded into neighbor weights;
//   relu; nt dwordx4 stores (1KB contiguous per wave per chain).
// ---------------------------------------------------------------------------
__global__ __launch_bounds__(256) void encoder_v12(
    const int*   __restrict__ idx,   // [S][N][32]
    const i32x2* __restrict__ xq,    // [S*N] fp8 rows (gather, L2-hot)
    const float* __restrict__ x,     // [S][N][5] fp32 (self, exact)
    const float* __restrict__ Wc,    // [2][5][128]
    const float* __restrict__ b,     // [128]
    float* __restrict__ out) {       // [S][N][128]
    const int lane = threadIdx.x & 63;
    const int sl   = lane & 31;
    const int half = lane >> 5;
    const int o0   = sl << 2;
    const int g    = (blockIdx.x * blockDim.x + threadIdx.x) >> 6;  // 0..24999

    // Fused weights (11 coalesced 16B loads/lane, once per 16 nodes);
    // fold mean(1/32) into the neighbor half.
    const float inv = 1.f / DEG_;
    float wa[F_][4], wb[F_][4];
#pragma unroll
    for (int f = 0; f < F_; ++f) {
        f32x4 a  = *reinterpret_cast<const f32x4*>(Wc + f * DOUT_ + o0);
        f32x4 bb = *reinterpret_cast<const f32x4*>(Wc + F_ * DOUT_ + f * DOUT_ + o0);
        wa[f][0] = a.x;        wa[f][1] = a.y;
        wa[f][2] = a.z;        wa[f][3] = a.w;
        wb[f][0] = bb.x * inv; wb[f][1] = bb.y * inv;
        wb[f][2] = bb.z * inv; wb[f][3] = bb.w * inv;
    }
    const f32x4 bias = *reinterpret_cast<const f32x4*>(b + o0);

    const int base = g * NODES_PER_WAVE;
    const int s    = base / N_;                  // uniform (16 | 50000)
    const i32x2* xs = xq + (size_t)s * N_;

    // --- issue ALL scattered work up front: 8 idx, 8 gathers ---
    int nb[8];
#pragma unroll
    for (int j = 0; j < 8; ++j) {
        const int node = base + 2 * j + half;
        nb[j] = __builtin_nontemporal_load(idx + (size_t)node * DEG_ + sl);
    }
    i32x2 gq[8];
#pragma unroll
    for (int j = 0; j < 8; ++j) gq[j] = xs[nb[j]];   // scattered 8B, L2

    // --- self features: 8 broadcast fp32 rows (exact) ---
    float sf[8][F_];
#pragma unroll
    for (int j = 0; j < 8; ++j) {
        const float* xr = x + (size_t)(base + 2 * j + half) * F_;
        __builtin_memcpy(&sf[j][0], xr, 16);     // f0..f3 (4B-aligned)
        sf[j][4] = xr[4];
    }

    // --- per chain: fp8->f16 unpack, butterfly, MLP, relu, nt store ---
#pragma unroll
    for (int j = 0; j < 8; ++j) {
        const int d0 = gq[j].x, d1 = gq[j].y;
        h2 v0 = { (_Float16)__builtin_amdgcn_cvt_f32_fp8(d0, 0),
                  (_Float16)__builtin_amdgcn_cvt_f32_fp8(d0, 1) };
        h2 v1 = { (_Float16)__builtin_amdgcn_cvt_f32_fp8(d0, 2),
                  (_Float16)__builtin_amdgcn_cvt_f32_fp8(d0, 3) };
        h2 v2 = { (_Float16)__builtin_amdgcn_cvt_f32_fp8(d1, 0), (_Float16)0.f };
#pragma unroll
        for (int m = 1; m < 32; m <<= 1) {       // butterfly within 32-lane half
            v0 += __builtin_bit_cast(h2, __shfl_xor(__builtin_bit_cast(int, v0), m));
            v1 += __builtin_bit_cast(h2, __shfl_xor(__builtin_bit_cast(int, v1), m));
            v2 += __builtin_bit_cast(h2, __shfl_xor(__builtin_bit_cast(int, v2), m));
        }
        const float nf[F_] = { (float)v0.x, (float)v0.y,
                               (float)v1.x, (float)v1.y, (float)v2.x };
        float y0 = bias.x, y1 = bias.y, y2 = bias.z, y3 = bias.w;
#pragma unroll
        for (int f = 0; f < F_; ++f) {
            y0 = fmaf(sf[j][f], wa[f][0], y0); y0 = fmaf(nf[f], wb[f][0], y0);
            y1 = fmaf(sf[j][f], wa[f][1], y1); y1 = fmaf(nf[f], wb[f][1], y1);
            y2 = fmaf(sf[j][f], wa[f][2], y2); y2 = fmaf(nf[f], wb[f][2], y2);
            y3 = fmaf(sf[j][f], wa[f][3], y3); y3 = fmaf(nf[f], wb[f][3], y3);
        }
        const int node = base + 2 * j + half;
        f32x4 yv = { fmaxf(y0, 0.f), fmaxf(y1, 0.f),
                     fmaxf(y2, 0.f), fmaxf(y3, 0.f) };
        __builtin_nontemporal_store(yv,
            reinterpret_cast<f32x4*>(out + (size_t)node * DOUT_ + o0));
    }
}

// ---------------------------------------------------------------------------
// Fallback (fp32 fused path) if ws_size is too small for the 3.2MB table.
// ---------------------------------------------------------------------------
__global__ __launch_bounds__(256) void encoder_f32(
    const float* __restrict__ x, const int* __restrict__ idx,
    const float* __restrict__ Wc, const float* __restrict__ b,
    float* __restrict__ out, int total_pairs) {
    const int lane = threadIdx.x & 63;
    const int sl   = lane & 31;
    const int half = lane >> 5;
    const int o0   = sl << 2;
    const int gwave  = (blockIdx.x * blockDim.x + threadIdx.x) >> 6;
    const int nwaves = (gridDim.x * blockDim.x) >> 6;
    float wa[F_][4], wb[F_][4];
#pragma unroll
    for (int f = 0; f < F_; ++f) {
        f32x4 a  = *reinterpret_cast<const f32x4*>(Wc + f * DOUT_ + o0);
        f32x4 bb = *reinterpret_cast<const f32x4*>(Wc + F_ * DOUT_ + f * DOUT_ + o0);
        wa[f][0] = a.x;  wa[f][1] = a.y;  wa[f][2] = a.z;  wa[f][3] = a.w;
        wb[f][0] = bb.x; wb[f][1] = bb.y; wb[f][2] = bb.z; wb[f][3] = bb.w;
    }
    const f32x4 bias = *reinterpret_cast<const f32x4*>(b + o0);
    for (int p = gwave; p < total_pairs; p += nwaves) {
        const int node = p * 2 + half;
        const int s    = node / N_;
        const int nb = idx[(size_t)node * DEG_ + sl];
        const float* xr = x + ((size_t)s * N_ + nb) * F_;
        float n0 = xr[0], n1 = xr[1], n2 = xr[2], n3 = xr[3], n4 = xr[4];
#pragma unroll
        for (int m = 1; m < 32; m <<= 1) {
            n0 += __shfl_xor(n0, m); n1 += __shfl_xor(n1, m); n2 += __shfl_xor(n2, m);
            n3 += __shfl_xor(n3, m); n4 += __shfl_xor(n4, m);
        }
        const float inv = 1.f / DEG_;
        const float nf[F_] = {n0 * inv, n1 * inv, n2 * inv, n3 * inv, n4 * inv};
        const float* xsp = x + (size_t)node * F_;
        const float sf[F_] = {xsp[0], xsp[1], xsp[2], xsp[3], xsp[4]};
        float y0 = bias.x, y1 = bias.y, y2 = bias.z, y3 = bias.w;
#pragma unroll
        for (int f = 0; f < F_; ++f) {
            y0 = fmaf(sf[f], wa[f][0], y0); y0 = fmaf(nf[f], wb[f][0], y0);
            y1 = fmaf(sf[f], wa[f][1], y1); y1 = fmaf(nf[f], wb[f][1], y1);
            y2 = fmaf(sf[f], wa[f][2], y2); y2 = fmaf(nf[f], wb[f][2], y2);
            y3 = fmaf(sf[f], wa[f][3], y3); y3 = fmaf(nf[f], wb[f][3], y3);
        }
        f32x4 yv = { fmaxf(y0, 0.f), fmaxf(y1, 0.f), fmaxf(y2, 0.f), fmaxf(y3, 0.f) };
        *reinterpret_cast<f32x4*>(out + (size_t)node * DOUT_ + o0) = yv;
    }
}

extern "C" void kernel_launch(void* const* d_in, const int* in_sizes, int n_in,
                              void* d_out, int out_size, void* d_ws, size_t ws_size,
                              hipStream_t stream) {
    const float* x   = (const float*)d_in[0];
    const int*   idx = (const int*)  d_in[1];
    const float* W1  = (const float*)d_in[2];
    const float* W   = (const float*)d_in[3];
    const float* b   = (const float*)d_in[4];
    float* out = (float*)d_out;

    const size_t wc_bytes = (size_t)2 * F_ * DOUT_ * sizeof(float);  // 5120
    const size_t xq_bytes = (size_t)TOTAL_NODES * sizeof(i32x2);     // 3.2 MB
    float* Wc = (float*)d_ws;

    hipLaunchKernelGGL(wc_precompute, dim3(5), dim3(256), 0, stream, W1, W, Wc);

    if (ws_size >= wc_bytes + xq_bytes) {
        i32x2* xq = (i32x2*)((char*)d_ws + wc_bytes);   // 5120 % 8 == 0
        hipLaunchKernelGGL(xpack_fp8, dim3((TOTAL_NODES + 255) / 256), dim3(256),
                           0, stream, x, xq);
        // Exact dispatch: 25000 waves, 4 waves/block -> 6250 blocks.
        hipLaunchKernelGGL(encoder_v12, dim3(GROUPS / 4), dim3(256), 0, stream,
                           idx, xq, x, Wc, b, out);
    } else {
        hipLaunchKernelGGL(encoder_f32, dim3(2048), dim3(256), 0, stream,
                           x, idx, Wc, b, out, TOTAL_NODES / 2);
    }
}

// Round 13
// 109.509 us; speedup vs baseline: 2.0206x; 1.0408x over previous
//
#include <hip/hip_runtime.h>
#include <cstddef>
#include <cstdint>

// Problem constants: S=8, N=50000, F=5, DEG=32, D_IN=D_OUT=128
static constexpr int S_    = 8;
static constexpr int N_    = 50000;
static constexpr int F_    = 5;
static constexpr int DEG_  = 32;
static constexpr int DOUT_ = 128;
static constexpr int TOTAL_NODES = S_ * N_;                   // 400000
static constexpr int NODES_PER_WAVE = 16;                     // 8 chains x 2 halves
static constexpr int GROUPS = TOTAL_NODES / NODES_PER_WAVE;   // 25000 (16 | 50000)

typedef float    f32x4 __attribute__((ext_vector_type(4)));
typedef int      i32x2 __attribute__((ext_vector_type(2)));
typedef _Float16 h2    __attribute__((ext_vector_type(2)));

// ---------------------------------------------------------------------------
// Kernel 1: fuse W_1 [5][128] with W [256][128] into Wc [2][5][128].
// ---------------------------------------------------------------------------
__global__ void wc_precompute(const float* __restrict__ W1,
                              const float* __restrict__ W,
                              float* __restrict__ Wc) {
    int t = blockIdx.x * blockDim.x + threadIdx.x;
    if (t >= 2 * F_ * DOUT_) return;
    int o = t & (DOUT_ - 1);
    int f = (t >> 7) % F_;
    int p = t / (F_ * DOUT_);
    const float* w1r  = W1 + f * 128;
    const float* wcol = W + (size_t)p * 128 * DOUT_ + o;
    float acc = 0.f;
#pragma unroll 8
    for (int d = 0; d < 128; ++d)
        acc = fmaf(w1r[d], wcol[(size_t)d * DOUT_], acc);
    Wc[t] = acc;
}

// ---------------------------------------------------------------------------
// Kernel 2: pack x rows into 8B fp8-e4m3 rows (3.2 MB table, L2-resident).
// ---------------------------------------------------------------------------
__global__ __launch_bounds__(256) void xpack_fp8(const float* __restrict__ x,
                                                 i32x2* __restrict__ xq) {
    int t = blockIdx.x * blockDim.x + threadIdx.x;
    if (t >= TOTAL_NODES) return;
    const float* r = x + (size_t)t * F_;
    int d0 = __builtin_amdgcn_cvt_pk_fp8_f32(r[0], r[1], 0, false);
    d0     = __builtin_amdgcn_cvt_pk_fp8_f32(r[2], r[3], d0, true);
    int d1 = __builtin_amdgcn_cvt_pk_fp8_f32(r[4], 0.f, 0, false);
    i32x2 v; v.x = d0; v.y = d1;
    xq[t] = v;
}

// ---------------------------------------------------------------------------
// Kernel 3: encoder v13 = v12 with ONE change: the 8 scattered gathers are
// DEVICE-SCOPE loads (bypass L1 -> served directly by the XCD L2). Probes
// whether the ~5.7 cy/line wall is L1 miss-allocate machinery.
// ---------------------------------------------------------------------------
__global__ __launch_bounds__(256) void encoder_v13(
    const int*   __restrict__ idx,   // [S][N][32]
    const i32x2* __restrict__ xq,    // [S*N] fp8 rows (gather, L2-hot)
    const float* __restrict__ x,     // [S][N][5] fp32 (self, exact)
    const float* __restrict__ Wc,    // [2][5][128]
    const float* __restrict__ b,     // [128]
    float* __restrict__ out) {       // [S][N][128]
    const int lane = threadIdx.x & 63;
    const int sl   = lane & 31;
    const int half = lane >> 5;
    const int o0   = sl << 2;
    const int g    = (blockIdx.x * blockDim.x + threadIdx.x) >> 6;  // 0..24999

    const float inv = 1.f / DEG_;
    float wa[F_][4], wb[F_][4];
#pragma unroll
    for (int f = 0; f < F_; ++f) {
        f32x4 a  = *reinterpret_cast<const f32x4*>(Wc + f * DOUT_ + o0);
        f32x4 bb = *reinterpret_cast<const f32x4*>(Wc + F_ * DOUT_ + f * DOUT_ + o0);
        wa[f][0] = a.x;        wa[f][1] = a.y;
        wa[f][2] = a.z;        wa[f][3] = a.w;
        wb[f][0] = bb.x * inv; wb[f][1] = bb.y * inv;
        wb[f][2] = bb.z * inv; wb[f][3] = bb.w * inv;
    }
    const f32x4 bias = *reinterpret_cast<const f32x4*>(b + o0);

    const int base = g * NODES_PER_WAVE;
    const int s    = base / N_;                  // uniform (16 | 50000)
    const i32x2* xs = xq + (size_t)s * N_;

    // --- 8 idx loads up front ---
    int nb[8];
#pragma unroll
    for (int j = 0; j < 8; ++j) {
        const int node = base + 2 * j + half;
        nb[j] = __builtin_nontemporal_load(idx + (size_t)node * DEG_ + sl);
    }
    // --- 8 scattered gathers, DEVICE SCOPE (L1 bypass), all in flight ---
    i32x2 gq[8];
#pragma unroll
    for (int j = 0; j < 8; ++j) {
        const long long* gp = reinterpret_cast<const long long*>(xs + nb[j]);
        const long long raw =
            __hip_atomic_load(gp, __ATOMIC_RELAXED, __HIP_MEMORY_SCOPE_AGENT);
        gq[j] = __builtin_bit_cast(i32x2, raw);
    }

    // --- self features: 8 broadcast fp32 rows (exact) ---
    float sf[8][F_];
#pragma unroll
    for (int j = 0; j < 8; ++j) {
        const float* xr = x + (size_t)(base + 2 * j + half) * F_;
        __builtin_memcpy(&sf[j][0], xr, 16);
        sf[j][4] = xr[4];
    }

    // --- per chain: fp8->f16 unpack, butterfly, MLP, relu, nt store ---
#pragma unroll
    for (int j = 0; j < 8; ++j) {
        const int d0 = gq[j].x, d1 = gq[j].y;
        h2 v0 = { (_Float16)__builtin_amdgcn_cvt_f32_fp8(d0, 0),
                  (_Float16)__builtin_amdgcn_cvt_f32_fp8(d0, 1) };
        h2 v1 = { (_Float16)__builtin_amdgcn_cvt_f32_fp8(d0, 2),
                  (_Float16)__builtin_amdgcn_cvt_f32_fp8(d0, 3) };
        h2 v2 = { (_Float16)__builtin_amdgcn_cvt_f32_fp8(d1, 0), (_Float16)0.f };
#pragma unroll
        for (int m = 1; m < 32; m <<= 1) {
            v0 += __builtin_bit_cast(h2, __shfl_xor(__builtin_bit_cast(int, v0), m));
            v1 += __builtin_bit_cast(h2, __shfl_xor(__builtin_bit_cast(int, v1), m));
            v2 += __builtin_bit_cast(h2, __shfl_xor(__builtin_bit_cast(int, v2), m));
        }
        const float nf[F_] = { (float)v0.x, (float)v0.y,
                               (float)v1.x, (float)v1.y, (float)v2.x };
        float y0 = bias.x, y1 = bias.y, y2 = bias.z, y3 = bias.w;
#pragma unroll
        for (int f = 0; f < F_; ++f) {
            y0 = fmaf(sf[j][f], wa[f][0], y0); y0 = fmaf(nf[f], wb[f][0], y0);
            y1 = fmaf(sf[j][f], wa[f][1], y1); y1 = fmaf(nf[f], wb[f][1], y1);
            y2 = fmaf(sf[j][f], wa[f][2], y2); y2 = fmaf(nf[f], wb[f][2], y2);
            y3 = fmaf(sf[j][f], wa[f][3], y3); y3 = fmaf(nf[f], wb[f][3], y3);
        }
        const int node = base + 2 * j + half;
        f32x4 yv = { fmaxf(y0, 0.f), fmaxf(y1, 0.f),
                     fmaxf(y2, 0.f), fmaxf(y3, 0.f) };
        __builtin_nontemporal_store(yv,
            reinterpret_cast<f32x4*>(out + (size_t)node * DOUT_ + o0));
    }
}

// ---------------------------------------------------------------------------
// Fallback (fp32 fused path) if ws_size is too small for the 3.2MB table.
// ---------------------------------------------------------------------------
__global__ __launch_bounds__(256) void encoder_f32(
    const float* __restrict__ x, const int* __restrict__ idx,
    const float* __restrict__ Wc, const float* __restrict__ b,
    float* __restrict__ out, int total_pairs) {
    const int lane = threadIdx.x & 63;
    const int sl   = lane & 31;
    const int half = lane >> 5;
    const int o0   = sl << 2;
    const int gwave  = (blockIdx.x * blockDim.x + threadIdx.x) >> 6;
    const int nwaves = (gridDim.x * blockDim.x) >> 6;
    float wa[F_][4], wb[F_][4];
#pragma unroll
    for (int f = 0; f < F_; ++f) {
        f32x4 a  = *reinterpret_cast<const f32x4*>(Wc + f * DOUT_ + o0);
        f32x4 bb = *reinterpret_cast<const f32x4*>(Wc + F_ * DOUT_ + f * DOUT_ + o0);
        wa[f][0] = a.x;  wa[f][1] = a.y;  wa[f][2] = a.z;  wa[f][3] = a.w;
        wb[f][0] = bb.x; wb[f][1] = bb.y; wb[f][2] = bb.z; wb[f][3] = bb.w;
    }
    const f32x4 bias = *reinterpret_cast<const f32x4*>(b + o0);
    for (int p = gwave; p < total_pairs; p += nwaves) {
        const int node = p * 2 + half;
        const int s    = node / N_;
        const int nb = idx[(size_t)node * DEG_ + sl];
        const float* xr = x + ((size_t)s * N_ + nb) * F_;
        float n0 = xr[0], n1 = xr[1], n2 = xr[2], n3 = xr[3], n4 = xr[4];
#pragma unroll
        for (int m = 1; m < 32; m <<= 1) {
            n0 += __shfl_xor(n0, m); n1 += __shfl_xor(n1, m); n2 += __shfl_xor(n2, m);
            n3 += __shfl_xor(n3, m); n4 += __shfl_xor(n4, m);
        }
        const float inv = 1.f / DEG_;
        const float nf[F_] = {n0 * inv, n1 * inv, n2 * inv, n3 * inv, n4 * inv};
        const float* xsp = x + (size_t)node * F_;
        const float sf[F_] = {xsp[0], xsp[1], xsp[2], xsp[3], xsp[4]};
        float y0 = bias.x, y1 = bias.y, y2 = bias.z, y3 = bias.w;
#pragma unroll
        for (int f = 0; f < F_; ++f) {
            y0 = fmaf(sf[f], wa[f][0], y0); y0 = fmaf(nf[f], wb[f][0], y0);
            y1 = fmaf(sf[f], wa[f][1], y1); y1 = fmaf(nf[f], wb[f][1], y1);
            y2 = fmaf(sf[f], wa[f][2], y2); y2 = fmaf(nf[f], wb[f][2], y2);
            y3 = fmaf(sf[f], wa[f][3], y3); y3 = fmaf(nf[f], wb[f][3], y3);
        }
        f32x4 yv = { fmaxf(y0, 0.f), fmaxf(y1, 0.f), fmaxf(y2, 0.f), fmaxf(y3, 0.f) };
        *reinterpret_cast<f32x4*>(out + (size_t)node * DOUT_ + o0) = yv;
    }
}

extern "C" void kernel_launch(void* const* d_in, const int* in_sizes, int n_in,
                              void* d_out, int out_size, void* d_ws, size_t ws_size,
                              hipStream_t stream) {
    const float* x   = (const float*)d_in[0];
    const int*   idx = (const int*)  d_in[1];
    const float* W1  = (const float*)d_in[2];
    const float* W   = (const float*)d_in[3];
    const float* b   = (const float*)d_in[4];
    float* out = (float*)d_out;

    const size_t wc_bytes = (size_t)2 * F_ * DOUT_ * sizeof(float);  // 5120
    const size_t xq_bytes = (size_t)TOTAL_NODES * sizeof(i32x2);     // 3.2 MB
    float* Wc = (float*)d_ws;

    hipLaunchKernelGGL(wc_precompute, dim3(5), dim3(256), 0, stream, W1, W, Wc);

    if (ws_size >= wc_bytes + xq_bytes) {
        i32x2* xq = (i32x2*)((char*)d_ws + wc_bytes);   // 5120 % 8 == 0
        hipLaunchKernelGGL(xpack_fp8, dim3((TOTAL_NODES + 255) / 256), dim3(256),
                           0, stream, x, xq);
        hipLaunchKernelGGL(encoder_v13, dim3(GROUPS / 4), dim3(256), 0, stream,
                           idx, xq, x, Wc, b, out);
    } else {
        hipLaunchKernelGGL(encoder_f32, dim3(2048), dim3(256), 0, stream,
                           x, idx, Wc, b, out, TOTAL_NODES / 2);
    }
}